// Round 1
// 335.427 us; speedup vs baseline: 1.0162x; 1.0162x over previous
//
#include <hip/hip_runtime.h>
#include <hip/hip_bf16.h>

// MinGRU: L=2 layers of  h_t = (1-z_t) h_{t-1} + z_t g(pre_t)
// R4: gemm_fused rebuilt as 256x128(dual) 4-phase counted-vmcnt pipeline
//     (T3+T4+T5 per m201 template): raw s_barrier, vmcnt(2)/vmcnt(4) counted
//     waits (never drain-0 in loop), setprio around MFMA clusters, 128 KiB
//     double-buffered dynamic LDS, row-XOR swizzle kept, XCD block swizzle.
//     Epilogue math / cv / Ac / Bc contract identical to R3.

#define L_ 2
#define B_ 8
#define S_ 2048
#define D_ 1024
#define H_ 1024
#define M_ (B_*S_)     // 16384
#define NC 32          // chunks per sequence
#define CL (S_/NC)     // 64 steps per chunk

typedef __bf16    bf16x8 __attribute__((ext_vector_type(8)));
typedef float     f32x4  __attribute__((ext_vector_type(4)));
typedef _Float16  h2     __attribute__((ext_vector_type(2)));
typedef _Float16  h4     __attribute__((ext_vector_type(4)));

__device__ __forceinline__ ushort f2bf(float f) {
    union { __hip_bfloat16 h; ushort u; } c;
    c.h = __float2bfloat16(f);   // RNE
    return c.u;
}

__device__ __forceinline__ void async16(const void* g, void* l) {
    __builtin_amdgcn_global_load_lds(
        (const __attribute__((address_space(1))) unsigned int*)g,
        (__attribute__((address_space(3))) unsigned int*)l, 16, 0, 0);
}

__global__ __launch_bounds__(256) void cast_f32_bf16(const float* __restrict__ in,
                                                     ushort* __restrict__ out, int n4) {
    int i = blockIdx.x * 256 + threadIdx.x;
    if (i >= n4) return;
    float4 v = ((const float4*)in)[i];
    ushort4 o;
    o.x = f2bf(v.x); o.y = f2bf(v.y); o.z = f2bf(v.z); o.w = f2bf(v.w);
    ((ushort4*)out)[i] = o;
}

// LDS layout: row R = 64 ushorts (8 chunks of 16B); logical chunk c stored at
// physical chunk c ^ (R&7).  Offset in ushorts:
#define SWZ(R, c) (((R) << 6) + ((((c) ^ ((R) & 7))) << 3))
#define MFMA16 __builtin_amdgcn_mfma_f32_16x16x32_bf16
#define FENCE() asm volatile("" ::: "memory")

// Fused dual-GEMM: k = A@Wz^T+bz, pre = A@Wh^T+bh over a 256m x 128n tile.
// cv = (sigmoid(-k), sigmoid(k)*g(pre)) fp16x2; per-64-row chunk affine -> Ac,Bc.
//
// LDS (ushort offsets, per buffer of 32768; buffers at 0 / 32768):
//   As: rows 0..255   -> [0, 16384)    (half0 rows 0..127 @0, half1 @8192)
//   Zs: rows 0..127   -> [16384, 24576)
//   Hs: rows 0..127   -> [24576, 32768)
// Stage order per tile: h0=A-lo, h1=A-hi, h2=Z, h3=H (2 loads/thread each).
// Phase p of tile t needs the half staged 4 phases earlier:
//   p0 (z, m-lo):  needs h0/h1/h2  -> vmcnt(2)
//   p1 (z, m-hi):  covered by p0's wait
//   p2 (h, m-hi):  needs h3        -> vmcnt(4)
//   p3 (h, m-lo):  register-only
__global__ __launch_bounds__(512, 2) void gemm_fused(const ushort* __restrict__ A,
                                                     const ushort* __restrict__ Wz,
                                                     const ushort* __restrict__ Wh,
                                                     const float* __restrict__ bz,
                                                     const float* __restrict__ bh,
                                                     h2* __restrict__ cv,
                                                     float* __restrict__ Ac,
                                                     float* __restrict__ Bc)
{
    extern __shared__ __align__(16) ushort sm[];     // 128 KiB dynamic

    const int tid  = threadIdx.x;
    const int lane = tid & 63;
    const int wave = tid >> 6;                       // 0..7
    // XCD-aware swizzle (512 blocks, 512%8==0 -> bijective): blocks sharing an
    // A-panel (same mblk mod group) land on the same XCD L2.
    const int bid  = (int)blockIdx.x;
    const int xcd  = bid & 7;
    const int k8   = bid >> 3;                       // 0..63
    const int nblk = k8 & 7;                         // 0..7
    const int mblk = ((k8 >> 3) << 3) + xcd;         // 0..63
    const int m0 = mblk << 8;                        // *256
    const int n0 = nblk << 7;                        // *128
    const int wm = (wave >> 2) << 7;                 // 0 / 128
    const int wn = (wave & 3) << 5;                  // 0/32/64/96
    const int lrow = lane & 15;
    const int lcq  = lane >> 4;                      // 0..3

    // staging geometry: 1024 16B-chunks per half, 2 per thread (e, e+512)
    const int e0 = tid, e1 = tid + 512;
    const int r0 = e0 >> 3, c0 = (((e0 & 7) ^ (r0 & 7)) << 3);
    const int r1 = e1 >> 3, c1 = (((e1 & 7) ^ (r1 & 7)) << 3);
    const uint offA0  = (uint)((m0 + r0) * D_ + c0);
    const uint offA0b = (uint)((m0 + r1) * D_ + c1);
    const uint offA1  = offA0  + (uint)(128 * D_);
    const uint offA1b = offA0b + (uint)(128 * D_);
    const uint offW0  = (uint)((n0 + r0) * D_ + c0);
    const uint offW0b = (uint)((n0 + r1) * D_ + c1);
    const int dj0 = wave << 9;                       // wave-uniform LDS dest
    const int dj1 = 4096 + (wave << 9);

    f32x4 accz[8][2] = {};
    f32x4 acch[8][2] = {};

    // prologue: stage tile 0 into buffer 0 (issue order h0,h1,h2,h3)
    async16(A  + offA0,  &sm[dj0]);
    async16(A  + offA0b, &sm[dj1]);
    async16(A  + offA1,  &sm[8192  + dj0]);
    async16(A  + offA1b, &sm[8192  + dj1]);
    async16(Wz + offW0,  &sm[16384 + dj0]);
    async16(Wz + offW0b, &sm[16384 + dj1]);
    async16(Wh + offW0,  &sm[24576 + dj0]);
    async16(Wh + offW0b, &sm[24576 + dj1]);

    #pragma unroll 2
    for (int t = 0; t < 16; ++t) {
        const int cur = (t & 1) << 15;               // *32768 ushorts
        const int nxt = cur ^ 32768;
        // last iter re-stages tile 15 (keeps vmcnt accounting uniform; drained
        // before LDS reuse below)
        const uint kbn = (uint)((t < 15 ? t + 1 : 15) << 6);
        bf16x8 a0[4][2], a1[4][2], zf[2][2], hf[2][2];

        // ---------------- phase 0: (z, m-lo) ----------------
        asm volatile("s_waitcnt vmcnt(2)" ::: "memory");
        __builtin_amdgcn_s_barrier();
        FENCE();
        #pragma unroll
        for (int mt = 0; mt < 4; ++mt)
            #pragma unroll
            for (int kk = 0; kk < 2; ++kk)
                a0[mt][kk] = *(const bf16x8*)&sm[cur + SWZ(wm + mt*16 + lrow, kk*4 + lcq)];
        #pragma unroll
        for (int nt = 0; nt < 2; ++nt)
            #pragma unroll
            for (int kk = 0; kk < 2; ++kk)
                zf[nt][kk] = *(const bf16x8*)&sm[cur + 16384 + SWZ(wn + nt*16 + lrow, kk*4 + lcq)];
        async16(A + offA0  + kbn, &sm[nxt + dj0]);
        async16(A + offA0b + kbn, &sm[nxt + dj1]);
        __builtin_amdgcn_s_setprio(1);
        #pragma unroll
        for (int kk = 0; kk < 2; ++kk)
            #pragma unroll
            for (int nt = 0; nt < 2; ++nt)
                #pragma unroll
                for (int mt = 0; mt < 4; ++mt)
                    accz[mt][nt] = MFMA16(a0[mt][kk], zf[nt][kk], accz[mt][nt], 0, 0, 0);
        __builtin_amdgcn_s_setprio(0);

        // ---------------- phase 1: (z, m-hi) ----------------
        __builtin_amdgcn_s_barrier();
        FENCE();
        #pragma unroll
        for (int mt = 0; mt < 4; ++mt)
            #pragma unroll
            for (int kk = 0; kk < 2; ++kk)
                a1[mt][kk] = *(const bf16x8*)&sm[cur + SWZ(wm + 64 + mt*16 + lrow, kk*4 + lcq)];
        async16(A + offA1  + kbn, &sm[nxt + 8192 + dj0]);
        async16(A + offA1b + kbn, &sm[nxt + 8192 + dj1]);
        __builtin_amdgcn_s_setprio(1);
        #pragma unroll
        for (int kk = 0; kk < 2; ++kk)
            #pragma unroll
            for (int nt = 0; nt < 2; ++nt)
                #pragma unroll
                for (int mt = 0; mt < 4; ++mt)
                    accz[4 + mt][nt] = MFMA16(a1[mt][kk], zf[nt][kk], accz[4 + mt][nt], 0, 0, 0);
        __builtin_amdgcn_s_setprio(0);

        // ---------------- phase 2: (h, m-hi) ----------------
        asm volatile("s_waitcnt vmcnt(4)" ::: "memory");
        __builtin_amdgcn_s_barrier();
        FENCE();
        #pragma unroll
        for (int nt = 0; nt < 2; ++nt)
            #pragma unroll
            for (int kk = 0; kk < 2; ++kk)
                hf[nt][kk] = *(const bf16x8*)&sm[cur + 24576 + SWZ(wn + nt*16 + lrow, kk*4 + lcq)];
        async16(Wz + offW0  + kbn, &sm[nxt + 16384 + dj0]);
        async16(Wz + offW0b + kbn, &sm[nxt + 16384 + dj1]);
        __builtin_amdgcn_s_setprio(1);
        #pragma unroll
        for (int kk = 0; kk < 2; ++kk)
            #pragma unroll
            for (int nt = 0; nt < 2; ++nt)
                #pragma unroll
                for (int mt = 0; mt < 4; ++mt)
                    acch[4 + mt][nt] = MFMA16(a1[mt][kk], hf[nt][kk], acch[4 + mt][nt], 0, 0, 0);
        __builtin_amdgcn_s_setprio(0);

        // ---------------- phase 3: (h, m-lo) ----------------
        __builtin_amdgcn_s_barrier();
        FENCE();
        async16(Wh + offW0  + kbn, &sm[nxt + 24576 + dj0]);
        async16(Wh + offW0b + kbn, &sm[nxt + 24576 + dj1]);
        __builtin_amdgcn_s_setprio(1);
        #pragma unroll
        for (int kk = 0; kk < 2; ++kk)
            #pragma unroll
            for (int nt = 0; nt < 2; ++nt)
                #pragma unroll
                for (int mt = 0; mt < 4; ++mt)
                    acch[mt][nt] = MFMA16(a0[mt][kk], hf[nt][kk], acch[mt][nt], 0, 0, 0);
        __builtin_amdgcn_s_setprio(0);
    }

    asm volatile("s_waitcnt vmcnt(0)" ::: "memory"); // drain stray restage loads
    __syncthreads();                                 // LDS now reusable

    // ---- epilogue: nonlinearity + cv write + per-4-row affines ----
    float2* seg = (float2*)sm;                       // [64 segs][stride 130] float2
    const int colq = lane & 15;
    const int rowq = (lane >> 4) << 2;
    #pragma unroll
    for (int nt = 0; nt < 2; ++nt) {
        const int n = n0 + wn + nt*16 + colq;
        const float bzv = bz[n];
        const float bhv = bh[n];
        #pragma unroll
        for (int mt = 0; mt < 8; ++mt) {
            float a = 1.f, bb = 0.f;                 // affine over this lane's 4 rows
            #pragma unroll
            for (int r = 0; r < 4; ++r) {
                const int m = m0 + wm + mt*16 + rowq + r;
                float kx = accz[mt][nt][r] + bzv;
                float p  = acch[mt][nt][r] + bhv;
                float e   = __expf(-fabsf(kx));
                float inv = 1.0f / (1.0f + e);
                float z   = (kx >= 0.f) ? inv     : e * inv;
                float c   = (kx >= 0.f) ? e * inv : inv;
                float g;
                if (p >= 0.f) g = p + 0.5f;
                else { float eg = __expf(p); g = eg / (1.0f + eg); }
                float v = z * g;
                h2 hv; hv[0] = (_Float16)c; hv[1] = (_Float16)v;
                cv[(size_t)m * H_ + n] = hv;
                bb = fmaf(c, bb, v);
                a *= c;
            }
            const int sidx = (wm >> 2) + mt*4 + (rowq >> 2);   // 0..63, time-ordered
            seg[sidx*130 + wn + nt*16 + colq] = make_float2(a, bb);
        }
    }
    __syncthreads();
    // 4 chunks of CL=64 per tile: chunk ch <- segs [16ch, 16ch+16)
    {
        const int col = tid & 127;
        const int ch  = tid >> 7;                    // 0..3
        float a = 1.f, bb = 0.f;
        #pragma unroll
        for (int s = 0; s < 16; ++s) {
            float2 e2 = seg[(ch*16 + s)*130 + col];
            bb = fmaf(e2.x, bb, e2.y);
            a *= e2.x;
        }
        const int b     = m0 >> 11;                  // S = 2048
        const int chunk = ((m0 >> 6) & (NC - 1)) + ch;
        const int q = (b*NC + chunk)*H_ + n0 + col;
        Ac[q] = a; Bc[q] = bb;
    }
}

// Scan over the NC chunk-affines per (b,h); emit incoming h per chunk.
__global__ __launch_bounds__(256) void scan_chunk_combine(const float* __restrict__ Ac,
                                                          const float* __restrict__ Bc,
                                                          float* __restrict__ hin)
{
    int q = blockIdx.x * 256 + threadIdx.x;          // 0 .. B*H-1
    int h = q & (H_-1);
    int b = q >> 10;
    float hcur = 0.5f;                               // h0 = g(0) = 0.5
    #pragma unroll
    for (int c = 0; c < NC; ++c) {
        int idx = (b*NC + c)*H_ + h;
        hin[idx] = hcur;
        hcur = fmaf(Ac[idx], hcur, Bc[idx]);
    }
}

// Re-scan each chunk with known incoming h; 2 h-values per thread (8B loads).
__global__ __launch_bounds__(256) void scan_emit(const h2* __restrict__ cv,
                                                 const float* __restrict__ hin,
                                                 float* __restrict__ outf,
                                                 ushort* __restrict__ outb,
                                                 const int write_bf16)
{
    int q = blockIdx.x * 256 + threadIdx.x;          // 0 .. B*NC*H/2-1
    int hp = (q & 511) * 2;                          // h, h+1
    int c = (q >> 9) & (NC-1);
    int b = q >> 14;
    size_t base = (size_t)(b*S_ + c*CL) * H_ + hp;
    int qh = (b*NC + c)*H_ + hp;
    float h0 = hin[qh], h1 = hin[qh + 1];
    if (write_bf16) {
        #pragma unroll 4
        for (int tt = 0; tt < CL; ++tt) {
            h4 e = *(const h4*)&cv[base + (size_t)tt * H_];
            h0 = fmaf((float)e[0], h0, (float)e[1]);
            h1 = fmaf((float)e[2], h1, (float)e[3]);
            ushort2 o; o.x = f2bf(h0); o.y = f2bf(h1);
            *(ushort2*)&outb[base + (size_t)tt * H_] = o;
        }
    } else {
        #pragma unroll 4
        for (int tt = 0; tt < CL; ++tt) {
            h4 e = *(const h4*)&cv[base + (size_t)tt * H_];
            h0 = fmaf((float)e[0], h0, (float)e[1]);
            h1 = fmaf((float)e[2], h1, (float)e[3]);
            *(float2*)&outf[base + (size_t)tt * H_] = make_float2(h0, h1);
        }
    }
}

extern "C" void kernel_launch(void* const* d_in, const int* in_sizes, int n_in,
                              void* d_out, int out_size, void* d_ws, size_t ws_size,
                              hipStream_t stream)
{
    const float* x  = (const float*)d_in[0];
    const float* Wz = (const float*)d_in[1];
    const float* bz = (const float*)d_in[2];
    const float* Wh = (const float*)d_in[3];
    const float* bh = (const float*)d_in[4];
    float* out = (float*)d_out;

    static bool attr_set = false;
    if (!attr_set) {
        (void)hipFuncSetAttribute(reinterpret_cast<const void*>(gemm_fused),
                                  hipFuncAttributeMaxDynamicSharedMemorySize, 131072);
        attr_set = true;
    }

    // workspace (~107 MiB)
    ushort* xb  = (ushort*)d_ws;                      // M*D bf16        (32 MiB)
    ushort* wzb = xb  + (size_t)M_*D_;                // L*H*D bf16      (4 MiB)
    ushort* whb = wzb + (size_t)L_*H_*D_;             // L*H*D bf16      (4 MiB)
    h2*     cv  = (h2*)(whb + (size_t)L_*H_*D_);      // M*H fp16x2      (64 MiB)
    float*  Ac  = (float*)(cv + (size_t)M_*H_);       // B*NC*H          (1 MiB)
    float*  Bc  = Ac + B_*NC*H_;
    float*  hin = Bc + B_*NC*H_;

    cast_f32_bf16<<<(M_*D_/4)/256, 256, 0, stream>>>(x, xb, M_*D_/4);
    cast_f32_bf16<<<(L_*H_*D_/4)/256, 256, 0, stream>>>(Wz, wzb, L_*H_*D_/4);
    cast_f32_bf16<<<(L_*H_*D_/4)/256, 256, 0, stream>>>(Wh, whb, L_*H_*D_/4);

    const int gemm_grid = (M_/256) * (H_/128);       // 512 blocks
    for (int l = 0; l < L_; ++l) {
        gemm_fused<<<gemm_grid, 512, 131072, stream>>>(xb,
                                                       wzb + (size_t)l*H_*D_,
                                                       whb + (size_t)l*H_*D_,
                                                       bz + l*H_, bh + l*H_,
                                                       cv, Ac, Bc);
        scan_chunk_combine<<<(B_*H_)/256, 256, 0, stream>>>(Ac, Bc, hin);
        scan_emit<<<(B_*NC*H_/2)/256, 256, 0, stream>>>(cv, hin, out, xb, (l == 0) ? 1 : 0);
    }
}